// Round 3
// baseline (40.683 us; speedup 1.0000x reference)
//
#include <hip/hip_runtime.h>

// out[b,c,h,w] = x[b,c,h,w] + emb[(h*16)/64, (w*16)/64, c]
//   x:   [16, 384, 64, 64] fp32 (100.7 MB)   emb: [1,16,16,384] fp32 (0.4 MB)
// Pure streaming add, HBM-bound. float4 along w: all 4 lanes of a vector
// share one emb scalar. Exact launch: nvec = 6,291,456 = 24576 blocks x 256,
// no tail, no loop. Non-temporal load/store (via clang ext_vector_type --
// HIP_vector_type is rejected by the builtin) keeps the streamed tensors
// from thrashing L2/L3 so x stays Infinity-Cache-resident across replays;
// emb load stays cached (reuse 256x).

typedef float f32x4 __attribute__((ext_vector_type(4)));

__global__ __launch_bounds__(256) void spatial_emb_add_kernel(
    const f32x4* __restrict__ x,
    const float* __restrict__ emb,
    f32x4* __restrict__ out) {
    unsigned v = blockIdx.x * 256u + threadIdx.x;
    unsigned f = v << 2;                    // flat element index
    unsigned w0 = f & 63u;                  // w of first lane (mult of 4)
    unsigned h  = (f >> 6) & 63u;           // h
    unsigned c  = (f >> 12) % 384u;         // channel (magic-mul)
    // emb index: ((h/4)*16 + (w0/4)) * 384 + c
    float e = emb[(((h >> 2) << 4) + (w0 >> 2)) * 384u + c];
    f32x4 xv = __builtin_nontemporal_load(&x[v]);
    f32x4 o = xv + e;                       // vector + broadcast scalar
    __builtin_nontemporal_store(o, &out[v]);
}

extern "C" void kernel_launch(void* const* d_in, const int* in_sizes, int n_in,
                              void* d_out, int out_size, void* d_ws, size_t ws_size,
                              hipStream_t stream) {
    const f32x4* x   = (const f32x4*)d_in[0];
    const float* emb = (const float*)d_in[1];
    f32x4* out = (f32x4*)d_out;

    const int nvec  = out_size / 4;          // 6,291,456
    const int block = 256;
    const int grid  = nvec / block;          // 24,576 exact, no tail
    spatial_emb_add_kernel<<<grid, block, 0, stream>>>(x, emb, out);
}

// Round 4
// 33.451 us; speedup vs baseline: 1.2162x; 1.2162x over previous
//
#include <hip/hip_runtime.h>

// out[b,c,h,w] = x[b,c,h,w] + emb[(h*16)/64, (w*16)/64, c]
//   x:   [16, 384, 64, 64] fp32 (100.7 MB)   emb: [1,16,16,384] fp32 (0.4 MB)
// Pure streaming add, HBM-bound. float4 along w: all 4 lanes of a vector
// share one emb scalar.
// Cache policy (R3 lesson): x read CACHED -- L3 (256 MB) retains it across
// graph replays (R1 showed FETCH = 49.5 MB, half resident). out written
// NON-TEMPORAL -- write-once data must not evict x from L3. NT loads on x
// regressed (40.7 us) by defeating exactly that residency.

typedef float f32x4 __attribute__((ext_vector_type(4)));

__global__ __launch_bounds__(256) void spatial_emb_add_kernel(
    const f32x4* __restrict__ x,
    const float* __restrict__ emb,
    f32x4* __restrict__ out) {
    unsigned v = blockIdx.x * 256u + threadIdx.x;
    unsigned f = v << 2;                    // flat element index
    unsigned w0 = f & 63u;                  // w of first lane (mult of 4)
    unsigned h  = (f >> 6) & 63u;           // h
    unsigned c  = (f >> 12) % 384u;         // channel (magic-mul)
    // emb index: ((h/4)*16 + (w0/4)) * 384 + c
    float e = emb[(((h >> 2) << 4) + (w0 >> 2)) * 384u + c];
    f32x4 xv = x[v];                        // cached: keep x L3-resident
    f32x4 o = xv + e;                       // vector + broadcast scalar
    __builtin_nontemporal_store(o, &out[v]);  // streaming: don't pollute L3
}

extern "C" void kernel_launch(void* const* d_in, const int* in_sizes, int n_in,
                              void* d_out, int out_size, void* d_ws, size_t ws_size,
                              hipStream_t stream) {
    const f32x4* x   = (const f32x4*)d_in[0];
    const float* emb = (const float*)d_in[1];
    f32x4* out = (f32x4*)d_out;

    const int nvec  = out_size / 4;          // 6,291,456
    const int block = 256;
    const int grid  = nvec / block;          // 24,576 exact, no tail
    spatial_emb_add_kernel<<<grid, block, 0, stream>>>(x, emb, out);
}